// Round 9
// baseline (817.435 us; speedup 1.0000x reference)
//
#include <hip/hip_runtime.h>
#include <cstdint>

// Problem constants
#define DM   512      // D_MODEL
#define DFF  2048     // D_FF
#define BSZ  4        // batch
#define LSEQ 1024     // sequence length
#define CHUNK 4       // timesteps staged per LDS buffer
#define NCHUNK (LSEQ / CHUNK)   // 256

// p += dpp-moved p (bound_ctrl=true -> lanes with no source contribute 0)
#define DPP_ADD(p, ctrl)                                                     \
    p += __int_as_float(__builtin_amdgcn_update_dpp(                         \
        0, __float_as_int(p), (ctrl), 0xF, 0xF, true))

// async global->LDS DMA, 16B per lane; LDS dst is wave-uniform base + lane*16
__device__ __forceinline__ void gload_lds16(const float4* g, float4* l) {
    __builtin_amdgcn_global_load_lds(
        (const __attribute__((address_space(1))) unsigned int*)g,
        (__attribute__((address_space(3))) unsigned int*)l,
        16, 0, 0);
}

// =====================================================================
// STP scan: ONE row per 64-lane wave, 8 f32 state elems/lane
// (row f's float4 indices {lane, lane+64}).
// grid = BSZ*DFF/4 = 2048 blocks x 256 thr (4 waves) = 8192 waves,
// 8 blocks/CU -> 32 waves/CU (100% occupancy ceiling). VGPR cap 64.
//
// hbuf arrives holding static_h = x@W1^T + b1; per step:
//   h_pre = sh_t + F.x_t ;  F' = R o F + (G o x_t)*h_pre
// hbuf[t,f] overwritten with h_pre (gelu applied by a later pass).
//
// x staged in CHUNK-step double-buffered LDS via global_load_lds
// (no staging VGPRs), 1 barrier/chunk. sh_t is wave-uniform: one
// 4-lane load per chunk, readlane per step; hp lives in SGPR; h_pre
// collected via cndmask into lanes 0..3, one 4-lane store per chunk.
// Reduce = 6 DPP adds (row_shr 1/2/4/8, bcast15, bcast31) -> lane 63.
// =====================================================================
__global__ __launch_bounds__(256, 8)
void stp_scan(const float* __restrict__ x,     // (B, L, DM)
              const float* __restrict__ Lam,   // (DFF, DM)
              const float* __restrict__ Gam,   // (DFF, DM)
              float* __restrict__ hbuf)        // (B*L, DFF) in: sh, out: h_pre
{
    const int tid  = threadIdx.x;
    const int lane = tid & 63;
    const int wid  = tid >> 6;              // 0..3: wave = row
    const int b    = blockIdx.x >> 9;       // 512 blocks per batch
    const int f    = ((blockIdx.x & 511) << 2) + wid;

    __shared__ float4 xs[2][CHUNK * 128];   // 2 x 8KB

    const float4* __restrict__ x4g =
        reinterpret_cast<const float4*>(x + (size_t)b * LSEQ * DM);
    float* __restrict__ hbase = hbuf + (size_t)b * LSEQ * DFF + f;

    // ---- state: 8 elems/lane ----
    float4 F0 = make_float4(0.f, 0.f, 0.f, 0.f), F1 = F0;
    float4 R0, R1, G0, G1;
    {
        const float4* lr = reinterpret_cast<const float4*>(Lam + (size_t)f * DM);
        const float4* gr = reinterpret_cast<const float4*>(Gam + (size_t)f * DM);
        float4 l0 = lr[lane], l1 = lr[lane + 64];
        R0.x = 1.0f / (1.0f + expf(l0.x));   // retention = 1 - sigmoid(Lam)
        R0.y = 1.0f / (1.0f + expf(l0.y));
        R0.z = 1.0f / (1.0f + expf(l0.z));
        R0.w = 1.0f / (1.0f + expf(l0.w));
        R1.x = 1.0f / (1.0f + expf(l1.x));
        R1.y = 1.0f / (1.0f + expf(l1.y));
        R1.z = 1.0f / (1.0f + expf(l1.z));
        R1.w = 1.0f / (1.0f + expf(l1.w));
        G0 = gr[lane];
        G1 = gr[lane + 64];
    }

    // wave wid stages float4 slices {2*wid, 2*wid+1} of each 512-float4 chunk
#define ISSUE_CHUNK(C, BUF)                                                  \
    {                                                                        \
        const float4* src_ = x4g + (size_t)(C) * (CHUNK * 128);              \
        gload_lds16(src_ + (wid * 2 + 0) * 64 + lane,                        \
                    &xs[BUF][(wid * 2 + 0) * 64]);                           \
        gload_lds16(src_ + (wid * 2 + 1) * 64 + lane,                        \
                    &xs[BUF][(wid * 2 + 1) * 64]);                           \
    }

    // ---- prologue: chunks 0,1 in flight; sh chunk 0 ----
    ISSUE_CHUNK(0, 0)
    ISSUE_CHUNK(1, 1)
    float shv = (lane < CHUNK) ? hbase[(size_t)lane * DFF] : 0.f;
    size_t shoff = (size_t)CHUNK * DFF;     // elem offset of chunk c+1 sh
    float* pst = hbase;                     // h_pre store base for chunk c
    __syncthreads();                        // drains both chunk DMAs

    #pragma unroll 1
    for (int c = 0; c < NCHUNK; ++c) {
        // prefetch next chunk's sh (consumed next iteration)
        float shvn = (lane < CHUNK) ? hbase[shoff + (size_t)lane * DFF] : 0.f;

        const float4* __restrict__ xb = &xs[c & 1][0];
        float hv = 0.f;

        #pragma unroll
        for (int s = 0; s < CHUNK; ++s) {
            float4 q0 = xb[s * 128 + lane];
            float4 q1 = xb[s * 128 + 64 + lane];

            // dot(F, x): 8 elems/lane, 2 chains
            float e0 = q0.x * F0.x;
            e0 = fmaf(q0.y, F0.y, e0);
            e0 = fmaf(q0.z, F0.z, e0);
            e0 = fmaf(q0.w, F0.w, e0);
            float e1 = q1.x * F1.x;
            e1 = fmaf(q1.y, F1.y, e1);
            e1 = fmaf(q1.z, F1.z, e1);
            e1 = fmaf(q1.w, F1.w, e1);
            float p = e0 + e1;

            // 64-lane reduce: prefix-shr + two bcasts
            DPP_ADD(p, 0x111);   // row_shr:1
            DPP_ADD(p, 0x112);   // row_shr:2
            DPP_ADD(p, 0x114);   // row_shr:4
            DPP_ADD(p, 0x118);   // row_shr:8   -> lanes 15/31/47/63 = 16-sums
            DPP_ADD(p, 0x142);   // row_bcast15 -> lane31 = sum(0..31), 63 = 32..63
            DPP_ADD(p, 0x143);   // row_bcast31 -> lane63 = full sum

            // + sh_t (wave-uniform, from SGPR)
            p += __int_as_float(__builtin_amdgcn_readlane(__float_as_int(shv), s));

            const int hpb = __builtin_amdgcn_readlane(__float_as_int(p), 63);
            const float hp = __int_as_float(hpb);   // uniform (SGPR)
            hv = (lane == s) ? hp : hv;             // collect hp_s into lane s

            // F' = R*F + (G*x)*hp
            F0.x = fmaf(G0.x * q0.x, hp, R0.x * F0.x);
            F0.y = fmaf(G0.y * q0.y, hp, R0.y * F0.y);
            F0.z = fmaf(G0.z * q0.z, hp, R0.z * F0.z);
            F0.w = fmaf(G0.w * q0.w, hp, R0.w * F0.w);
            F1.x = fmaf(G1.x * q1.x, hp, R1.x * F1.x);
            F1.y = fmaf(G1.y * q1.y, hp, R1.y * F1.y);
            F1.z = fmaf(G1.z * q1.z, hp, R1.z * F1.z);
            F1.w = fmaf(G1.w * q1.w, hp, R1.w * F1.w);
        }

        __syncthreads();   // all waves done reading xs[c&1]; next DMA drained

        // refill the buffer we just finished (flies during next chunk's compute)
        if (c + 2 < NCHUNK) ISSUE_CHUNK(c + 2, c & 1)

        // store this chunk's h_pre (lanes 0..3 hold hp_0..3)
        if (lane < CHUNK) pst[(size_t)lane * DFF] = hv;
        pst += (size_t)CHUNK * DFF;

        shv = shvn;
        if (c + 2 < NCHUNK) shoff += (size_t)CHUNK * DFF;
    }
#undef ISSUE_CHUNK
}

// =====================================================================
// Elementwise exact-gelu pass, in place over hbuf.
// =====================================================================
__global__ __launch_bounds__(256)
void gelu_inplace(float4* __restrict__ p, int n4)
{
    int i = blockIdx.x * blockDim.x + threadIdx.x;
    const int stride = gridDim.x * blockDim.x;
    for (; i < n4; i += stride) {
        float4 v = p[i];
        v.x = 0.5f * v.x * (1.0f + erff(v.x * 0.70710678118654752f));
        v.y = 0.5f * v.y * (1.0f + erff(v.y * 0.70710678118654752f));
        v.z = 0.5f * v.z * (1.0f + erff(v.z * 0.70710678118654752f));
        v.w = 0.5f * v.w * (1.0f + erff(v.w * 0.70710678118654752f));
        p[i] = v;
    }
}

// =====================================================================
// C[M,N] = A[M,K] . B[N,K]^T + bias[N]   (fp32 NT). 64x64 tile, BK=16,
// 256 threads, 4x4 per thread. Used for both static_h and the output.
// =====================================================================
__global__ __launch_bounds__(256)
void gemm_nt_bias(const float* __restrict__ A,
                  const float* __restrict__ Bm,
                  const float* __restrict__ bias,
                  float* __restrict__ C,
                  int M, int N, int K)
{
    __shared__ float As[16][68];
    __shared__ float Bs[16][68];

    const int tid = threadIdx.x;
    const int tx  = tid & 15;
    const int ty  = tid >> 4;
    const int row0 = blockIdx.y * 64;
    const int col0 = blockIdx.x * 64;

    const int lr = tid >> 2;          // 0..63
    const int lk = (tid & 3) << 2;    // 0,4,8,12

    const float* Aptr = A  + (size_t)(row0 + lr) * K + lk;
    const float* Bptr = Bm + (size_t)(col0 + lr) * K + lk;

    float acc[4][4] = {};
    float4 av = *reinterpret_cast<const float4*>(Aptr);
    float4 bv = *reinterpret_cast<const float4*>(Bptr);

    const int NT = K >> 4;
    for (int kt = 0; kt < NT; ++kt) {
        __syncthreads();
        As[lk + 0][lr] = av.x; As[lk + 1][lr] = av.y;
        As[lk + 2][lr] = av.z; As[lk + 3][lr] = av.w;
        Bs[lk + 0][lr] = bv.x; Bs[lk + 1][lr] = bv.y;
        Bs[lk + 2][lr] = bv.z; Bs[lk + 3][lr] = bv.w;
        __syncthreads();

        if (kt + 1 < NT) {
            av = *reinterpret_cast<const float4*>(Aptr + (kt + 1) * 16);
            bv = *reinterpret_cast<const float4*>(Bptr + (kt + 1) * 16);
        }

        #pragma unroll
        for (int k = 0; k < 16; ++k) {
            float4 a = *reinterpret_cast<const float4*>(&As[k][ty * 4]);
            float4 bb = *reinterpret_cast<const float4*>(&Bs[k][tx * 4]);
            acc[0][0] = fmaf(a.x, bb.x, acc[0][0]);
            acc[0][1] = fmaf(a.x, bb.y, acc[0][1]);
            acc[0][2] = fmaf(a.x, bb.z, acc[0][2]);
            acc[0][3] = fmaf(a.x, bb.w, acc[0][3]);
            acc[1][0] = fmaf(a.y, bb.x, acc[1][0]);
            acc[1][1] = fmaf(a.y, bb.y, acc[1][1]);
            acc[1][2] = fmaf(a.y, bb.z, acc[1][2]);
            acc[1][3] = fmaf(a.y, bb.w, acc[1][3]);
            acc[2][0] = fmaf(a.z, bb.x, acc[2][0]);
            acc[2][1] = fmaf(a.z, bb.y, acc[2][1]);
            acc[2][2] = fmaf(a.z, bb.z, acc[2][2]);
            acc[2][3] = fmaf(a.z, bb.w, acc[2][3]);
            acc[3][0] = fmaf(a.w, bb.x, acc[3][0]);
            acc[3][1] = fmaf(a.w, bb.y, acc[3][1]);
            acc[3][2] = fmaf(a.w, bb.z, acc[3][2]);
            acc[3][3] = fmaf(a.w, bb.w, acc[3][3]);
        }
    }

    const float4 bb = *reinterpret_cast<const float4*>(&bias[col0 + tx * 4]);
    #pragma unroll
    for (int i = 0; i < 4; ++i) {
        float4 o;
        o.x = acc[i][0] + bb.x;
        o.y = acc[i][1] + bb.y;
        o.z = acc[i][2] + bb.z;
        o.w = acc[i][3] + bb.w;
        *reinterpret_cast<float4*>(&C[(size_t)(row0 + ty * 4 + i) * N + col0 + tx * 4]) = o;
    }
}

// =====================================================================
extern "C" void kernel_launch(void* const* d_in, const int* in_sizes, int n_in,
                              void* d_out, int out_size, void* d_ws, size_t ws_size,
                              hipStream_t stream)
{
    const float* x   = (const float*)d_in[0];  // (4,1024,512)
    const float* W1  = (const float*)d_in[1];  // (2048,512)
    const float* b1  = (const float*)d_in[2];  // (2048)
    const float* W2  = (const float*)d_in[3];  // (512,2048)
    const float* b2  = (const float*)d_in[4];  // (512)
    const float* Lam = (const float*)d_in[5];  // (2048,512)
    const float* Gam = (const float*)d_in[6];  // (2048,512)
    float* out  = (float*)d_out;               // (4,1024,512)
    float* hbuf = (float*)d_ws;                // (4096, 2048) f32 = 32 MB

    const int M = BSZ * LSEQ;                  // 4096

    // 1) static_h = x @ W1^T + b1  -> hbuf
    gemm_nt_bias<<<dim3(DFF / 64, M / 64), dim3(256), 0, stream>>>(
        x, W1, b1, hbuf, M, DFF, DM);

    // 2) scan: hbuf <- h_pre (in place). 2048 blocks x 4 waves x 1 row.
    stp_scan<<<dim3(BSZ * (DFF / 4)), dim3(256), 0, stream>>>(x, Lam, Gam, hbuf);

    // 3) hbuf <- gelu(hbuf)
    gelu_inplace<<<dim3(2048), dim3(256), 0, stream>>>(
        reinterpret_cast<float4*>(hbuf), M * DFF / 4);

    // 4) out = hbuf @ W2^T + b2
    gemm_nt_bias<<<dim3(DM / 64, M / 64), dim3(256), 0, stream>>>(
        hbuf, W2, b2, out, M, DM, DFF);
}